// Round 13
// baseline (129.198 us; speedup 1.0000x reference)
//
#include <hip/hip_runtime.h>
#include <math.h>

// GAT 2-layer forward. N=50000 nodes, E=800000 edges, D=128, H=4 heads, F=32.
constexpr int NN = 50000;
constexpr int NE = 800000;
constexpr int D  = 128;
constexpr int NH = 4;
constexpr int NBUK = (NN + 255) / 256;   // 196 dst-range buckets of 256 nodes
constexpr int EPB  = 2048;               // edges per partition block
constexpr int NPB  = (NE + EPB - 1) / EPB;  // 391
constexpr int CAPS = 4608;               // srcs per-bucket stride (mean 4082 + 8σ)
constexpr int SRC_MID = 25000;           // src-half split for L2 phasing
constexpr int FR_PER_LAYER = 9 * 4 * 64; // 9 B-tiles (8 W + 1 alpha-C) per layer
constexpr int RBLK = (2 * FR_PER_LAYER) / 256;   // 18 repack blocks (exact)

typedef __attribute__((ext_vector_type(8))) short short8v;  // 8 bf16 (4 VGPR)
typedef __attribute__((ext_vector_type(4))) float f32x4;    // MFMA accumulator

__device__ inline unsigned short rne_bf16(float f) {
    unsigned bits = __float_as_uint(f);
    return (unsigned short)((bits + 0x7FFFu + ((bits >> 16) & 1u)) >> 16);
}

// acc += a.bf16[0]*b.bf16[0] + a.bf16[1]*b.bf16[1]  (f32 accumulate)
#define DOT2BF(accv, pa, pb) \
    asm("v_dot2_f32_bf16 %0, %1, %2, %0" : "+v"(accv) : "v"(pa), "v"(pb))

// ============== K1: repack ∥ partition (fused, no global atomics) ===========
__device__ __forceinline__ void repack_body(
    int tid, const float* __restrict__ W, const float* __restrict__ a_src,
    const float* __restrict__ a_dst, unsigned short* __restrict__ Wpk)
{
    int layer = tid / FR_PER_LAYER;
    int rest  = tid % FR_PER_LAYER;
    int tile  = rest >> 8;            // 0..8
    int kstep = (rest >> 6) & 3;
    int lane  = rest & 63;
    int col   = lane & 15;
    int kbase = kstep * 32 + (lane >> 4) * 8;
    const float* Wl = W + (size_t)layer * D * D;
    unsigned short v[8];
    if (tile < 8) {
        int c = tile * 16 + col;
        #pragma unroll
        for (int j = 0; j < 8; ++j) v[j] = rne_bf16(Wl[(kbase + j) * D + c]);
    } else {
        #pragma unroll
        for (int j = 0; j < 8; ++j) v[j] = 0;
        if (col < 8) {
            const float* av = ((col < 4) ? a_src : a_dst) + layer * D + (col & 3) * 32;
            const int hbase = (col & 3) * 32;
            for (int j = 0; j < 8; ++j) {
                float sum = 0.f;
                const float* wr = Wl + (size_t)(kbase + j) * D + hbase;
                #pragma unroll
                for (int jj = 0; jj < 32; ++jj) sum = fmaf(wr[jj], av[jj], sum);
                v[j] = rne_bf16(sum);
            }
        }
    }
    *(uint4*)(Wpk + (size_t)tid * 8) = *(const uint4*)v;
}

__global__ __launch_bounds__(256) void prep_kernel(
    const float* __restrict__ W, const float* __restrict__ a_src,
    const float* __restrict__ a_dst, unsigned short* __restrict__ Wpk,
    const int* __restrict__ src, const int* __restrict__ dst,
    unsigned* __restrict__ outbuf, int* __restrict__ cnts,
    int* __restrict__ lofs)
{
    __shared__ union {
        struct { unsigned stage[EPB]; int cnt[NBUK]; int fill[NBUK]; int sc[256]; } p;
        int dummy;
    } sm;
    if (blockIdx.x < RBLK) {
        repack_body(blockIdx.x * 256 + threadIdx.x, W, a_src, a_dst, Wpk);
        return;
    }
    const int pb = blockIdx.x - RBLK;
    const int t  = threadIdx.x;
    for (int i = t; i < NBUK; i += 256) sm.p.cnt[i] = 0;
    __syncthreads();
    const int base = pb * EPB;
    const int tot  = min(NE - base, EPB);
    unsigned pk[8]; int bk[8];
    #pragma unroll
    for (int i = 0; i < 8; ++i) {
        int e = base + i * 256 + t;
        bool ok = (e < NE);
        int s = ok ? src[e] : 0;
        int d = ok ? dst[e] : 0;
        bk[i] = d >> 8;
        pk[i] = (unsigned)s | ((unsigned)(d & 255) << 16) | ((unsigned)bk[i] << 24);
        if (ok) atomicAdd(&sm.p.cnt[bk[i]], 1);
    }
    __syncthreads();
    int v = (t < NBUK) ? sm.p.cnt[t] : 0;
    sm.p.sc[t] = v;
    __syncthreads();
    for (int off = 1; off < 256; off <<= 1) {
        int u = (t >= off) ? sm.p.sc[t - off] : 0;
        __syncthreads();
        sm.p.sc[t] += u;
        __syncthreads();
    }
    const int excl = sm.p.sc[t] - v;
    if (t < NBUK) {
        sm.p.fill[t] = excl;
        cnts[t * NPB + pb] = v;
        lofs[t * NPB + pb] = excl;
    }
    __syncthreads();
    #pragma unroll
    for (int i = 0; i < 8; ++i) {
        int e = base + i * 256 + t;
        if (e < NE) {
            int pos = atomicAdd(&sm.p.fill[bk[i]], 1);
            sm.p.stage[pos] = pk[i];
        }
    }
    __syncthreads();
    for (int i = t; i < tot; i += 256) outbuf[base + i] = sm.p.stage[i];
}

// ---------------- gemm body: h = x @ W via MFMA; alphas via C tile ----------
template<int BF16IN>
__device__ __forceinline__ void gemm_body(
    int blk, unsigned short* __restrict__ xl, const void* __restrict__ xin,
    const unsigned short* __restrict__ Wpk, unsigned short* __restrict__ hb,
    float* __restrict__ alpha_s, float* __restrict__ alpha_d)
{
    const int t = threadIdx.x;
    const int row0 = blk * 64;

    if constexpr (BF16IN) {
        const unsigned short* xb = (const unsigned short*)xin;
        #pragma unroll
        for (int it = 0; it < 4; ++it) {
            int idx = it * 256 + t;
            int r   = idx >> 4;
            int c8  = (idx & 15) * 8;
            int n   = row0 + r;
            uint4 v = {0u, 0u, 0u, 0u};
            if (n < NN) v = *(const uint4*)(xb + (size_t)n * D + c8);
            *(uint4*)(xl + r * 128 + (c8 ^ ((r & 7) << 3))) = v;
        }
    } else {
        const float* xf = (const float*)xin;
        #pragma unroll
        for (int it = 0; it < 8; ++it) {
            int idx = it * 256 + t;
            int r   = idx >> 5;
            int c4  = (idx & 31) * 4;
            int n   = row0 + r;
            float4 v;
            if (n < NN) v = *(const float4*)(xf + (size_t)n * D + c4);
            else { v.x = 0.f; v.y = 0.f; v.z = 0.f; v.w = 0.f; }
            unsigned p0 = ((unsigned)rne_bf16(v.y) << 16) | rne_bf16(v.x);
            unsigned p1 = ((unsigned)rne_bf16(v.w) << 16) | rne_bf16(v.z);
            uint2 pv; pv.x = p0; pv.y = p1;
            *(uint2*)(xl + r * 128 + (c4 ^ ((r & 7) << 3))) = pv;
        }
    }
    __syncthreads();

    const int wv  = t >> 6;
    const int l   = t & 63;
    const int l15 = l & 15;
    const int g   = l >> 4;
    const int strip = wv * 16;
    const int arow  = strip + l15;

    f32x4 acc[9];
    #pragma unroll
    for (int i = 0; i < 9; ++i) acc[i] = (f32x4){0.f, 0.f, 0.f, 0.f};

    #pragma unroll
    for (int ks = 0; ks < 4; ++ks) {
        const int k0 = ks * 32 + g * 8;
        short8v a = *(const short8v*)(xl + arow * 128 + (k0 ^ ((arow & 7) << 3)));
        #pragma unroll
        for (int tl = 0; tl < 9; ++tl) {
            short8v b = *(const short8v*)(Wpk + ((size_t)(tl * 4 + ks) * 64 + l) * 8);
            acc[tl] = __builtin_amdgcn_mfma_f32_16x16x32_bf16(a, b, acc[tl], 0, 0, 0);
        }
    }

    #pragma unroll
    for (int r = 0; r < 4; ++r) {
        const int n = row0 + strip + g * 4 + r;
        if (n < NN) {
            #pragma unroll
            for (int tl = 0; tl < 8; ++tl)
                hb[(size_t)n * D + tl * 16 + l15] = rne_bf16(acc[tl][r]);
            const float av = acc[8][r];
            if (l15 < 4)      alpha_s[n * NH + l15]       = av;
            else if (l15 < 8) alpha_d[n * NH + (l15 - 4)] = av;
        }
    }
}

// ============== K2: bucket_sort (512-bin: dstlo, src-half) ∥ gemm-L0 ========
template<int BF16IN>
__global__ __launch_bounds__(256) void sort_gemm_kernel(
    const unsigned* __restrict__ outbuf, const int* __restrict__ cnts,
    const int* __restrict__ lofs, int2* __restrict__ rowse,
    int* __restrict__ midp, unsigned short* __restrict__ srcs,
    const void* __restrict__ xin, const unsigned short* __restrict__ Wpk,
    unsigned short* __restrict__ hb, float* __restrict__ alpha_s,
    float* __restrict__ alpha_d)
{
    __shared__ union {
        struct { unsigned stage[CAPS]; int hist[512]; int run[512]; int sc[256]; int cursor; } s;
        unsigned short xl[64 * 128];
    } sm;

    if (blockIdx.x >= NBUK) {
        gemm_body<BF16IN>(blockIdx.x - NBUK, sm.xl, xin, Wpk, hb, alpha_s, alpha_d);
        return;
    }
    const int b = blockIdx.x;
    const int t = threadIdx.x;
    if (t == 0) sm.s.cursor = 0;
    sm.s.hist[t] = 0; sm.s.hist[t + 256] = 0;
    __syncthreads();
    // copy phase: pull this bucket's segment from each partition-block region
    for (int pb = t; pb < NPB; pb += 256) {
        int len = cnts[b * NPB + pb];
        if (len > 0) {
            int off = lofs[b * NPB + pb];
            int pos = atomicAdd(&sm.s.cursor, len);
            const unsigned* sp = outbuf + pb * EPB + off;
            for (int k = 0; k < len; ++k)
                if (pos + k < CAPS) sm.s.stage[pos + k] = sp[k];
        }
    }
    __syncthreads();
    const int tot = min(sm.s.cursor, CAPS);
    for (int i = t; i < tot; i += 256) {
        unsigned p = sm.s.stage[i];
        int key = ((int)((p >> 16) & 255u) << 1) | (int)((p & 0xFFFFu) >= (unsigned)SRC_MID);
        atomicAdd(&sm.s.hist[key], 1);
    }
    __syncthreads();
    // pair-scan: node u owns bins 2u (src<MID) and 2u+1 (src>=MID)
    const int v0 = sm.s.hist[2 * t];
    const int v1 = sm.s.hist[2 * t + 1];
    const int pv = v0 + v1;
    sm.s.sc[t] = pv;
    __syncthreads();
    for (int off = 1; off < 256; off <<= 1) {
        int u = (t >= off) ? sm.s.sc[t - off] : 0;
        __syncthreads();
        sm.s.sc[t] += u;
        __syncthreads();
    }
    const int pexcl = sm.s.sc[t] - pv;
    const int node = b * 256 + t;
    if (node < NN) {
        int2 se; se.x = b * CAPS + pexcl; se.y = b * CAPS + pexcl + pv;
        rowse[node] = se;
        midp[node]  = se.x + v0;
    }
    sm.s.run[2 * t]     = pexcl;
    sm.s.run[2 * t + 1] = pexcl + v0;
    __syncthreads();
    for (int i = t; i < tot; i += 256) {
        unsigned p = sm.s.stage[i];
        int key = ((int)((p >> 16) & 255u) << 1) | (int)((p & 0xFFFFu) >= (unsigned)SRC_MID);
        int pos = atomicAdd(&sm.s.run[key], 1);
        srcs[b * CAPS + pos] = (unsigned short)(p & 0xFFFFu);
    }
}

// Standalone gemm for layer 1
template<int BF16IN>
__global__ __launch_bounds__(256) void gemm_alpha_kernel(
    const void* __restrict__ xin, const unsigned short* __restrict__ Wpk,
    unsigned short* __restrict__ hb, float* __restrict__ alpha_s,
    float* __restrict__ alpha_d)
{
    __shared__ unsigned short xl[64 * 128];
    gemm_body<BF16IN>(blockIdx.x, xl, xin, Wpk, hb, alpha_s, alpha_d);
}

// ---------------- per-dst-node gather + softmax + aggregate + epilogue ------
// Quarter-wave per node; lane owns 8 cols; 2 edges/iter via v_perm_b32 +
// v_dot2_f32_bf16 with 2-slot software pipeline. Edges are processed in TWO
// src-range phases ([start,mid): src<25000, then [mid,end)) so co-resident
// blocks touch a 6.4MB hb working set per phase -> higher L2 hit rate.
#define SHUF2(MI, SA, SB, WP) {                                          \
    int eA = lb + (MI), eB = eA + 1;                                     \
    SA = __shfl(msrc, eA); SB = __shfl(msrc, eB);                        \
    unsigned a01 = (unsigned)__shfl((int)uw01, eA);                      \
    unsigned a23 = (unsigned)__shfl((int)uw23, eA);                      \
    unsigned c01 = (unsigned)__shfl((int)uw01, eB);                      \
    unsigned c23 = (unsigned)__shfl((int)uw23, eB);                      \
    unsigned uwA = (head < 2) ? a01 : a23;                               \
    unsigned uwB = (head < 2) ? c01 : c23;                               \
    WP = __builtin_amdgcn_perm(uwB, uwA, wsel); }

#define ROWLD(S) (*(const uint4*)(hb + ((size_t)(S) << 7) + (ql << 3)))

#define DOT2BLOCK(WP, HA, HB) {                                               \
    DOT2BF(den, WP, ones);                                                    \
    unsigned p_;                                                              \
    p_ = __builtin_amdgcn_perm(HB.x, HA.x, 0x05040100u); DOT2BF(acc[0], p_, WP); \
    p_ = __builtin_amdgcn_perm(HB.x, HA.x, 0x07060302u); DOT2BF(acc[1], p_, WP); \
    p_ = __builtin_amdgcn_perm(HB.y, HA.y, 0x05040100u); DOT2BF(acc[2], p_, WP); \
    p_ = __builtin_amdgcn_perm(HB.y, HA.y, 0x07060302u); DOT2BF(acc[3], p_, WP); \
    p_ = __builtin_amdgcn_perm(HB.z, HA.z, 0x05040100u); DOT2BF(acc[4], p_, WP); \
    p_ = __builtin_amdgcn_perm(HB.z, HA.z, 0x07060302u); DOT2BF(acc[5], p_, WP); \
    p_ = __builtin_amdgcn_perm(HB.w, HA.w, 0x05040100u); DOT2BF(acc[6], p_, WP); \
    p_ = __builtin_amdgcn_perm(HB.w, HA.w, 0x07060302u); DOT2BF(acc[7], p_, WP); }

template<int IN_BF16, int OUT_BF16, int ACT>
__global__ __launch_bounds__(256) void gather_kernel(
    const unsigned short* __restrict__ hb, const float* __restrict__ alpha_s,
    const float* __restrict__ alpha_d, const int2* __restrict__ rowse,
    const int* __restrict__ midp, const unsigned short* __restrict__ srcs,
    const void* __restrict__ x_in, const float* __restrict__ bias,
    void* __restrict__ out)
{
    const int lane = threadIdx.x & 63;
    const int q    = lane >> 4;
    const int ql   = lane & 15;
    const int head = ql >> 2;
    const int lb   = q * 16;
    const int n = blockIdx.x * 16 + (threadIdx.x >> 6) * 4 + q;
    if (n >= NN) return;

    const int2 se = rowse[n];
    const int md  = midp[n];
    const float4 ad4 = *(const float4*)&alpha_d[n * NH];
    const unsigned wsel = (head & 1) ? 0x07060302u : 0x05040100u;
    const unsigned ones = 0x3F803F80u;

    float acc[8];
    #pragma unroll
    for (int c = 0; c < 8; ++c) acc[c] = 0.f;
    float den = 0.f;

    auto run_range = [&](int rs, int re) {
        for (int base = rs; base < re; base += 16) {
            const int cnt = min(16, re - base);
            int msrc = 0;
            unsigned uw01 = 0, uw23 = 0;
            if (ql < cnt) {
                msrc = srcs[base + ql];
                const float4 as4 = *(const float4*)&alpha_s[msrc * NH];
                float e0 = as4.x + ad4.x; e0 = (e0 > 0.f) ? e0 : 0.2f * e0;
                float e1 = as4.y + ad4.y; e1 = (e1 > 0.f) ? e1 : 0.2f * e1;
                float e2 = as4.z + ad4.z; e2 = (e2 > 0.f) ? e2 : 0.2f * e2;
                float e3 = as4.w + ad4.w; e3 = (e3 > 0.f) ? e3 : 0.2f * e3;
                float w0 = __expf(e0), w1 = __expf(e1);
                float w2 = __expf(e2), w3 = __expf(e3);
                uw01 = ((unsigned)rne_bf16(w1) << 16) | rne_bf16(w0);
                uw23 = ((unsigned)rne_bf16(w3) << 16) | rne_bf16(w2);
            }
            const int mm = (cnt + 1) & ~1;   // phantom odd edge: w=0, src=0

            int sxa, sxb, sya, syb;
            unsigned wpX, wpY;
            uint4 hxa, hxb, hya, hyb;
            SHUF2(0, sxa, sxb, wpX);
            hxa = ROWLD(sxa); hxb = ROWLD(sxb);
            if (mm > 2) {
                SHUF2(2, sya, syb, wpY);
                hya = ROWLD(sya); hyb = ROWLD(syb);
            }
            int m = 0;
            while (true) {
                DOT2BLOCK(wpX, hxa, hxb);
                m += 2;
                if (m >= mm) break;
                if (m + 2 < mm) {
                    SHUF2(m + 2, sxa, sxb, wpX);
                    hxa = ROWLD(sxa); hxb = ROWLD(sxb);
                }
                DOT2BLOCK(wpY, hya, hyb);
                m += 2;
                if (m >= mm) break;
                if (m + 2 < mm) {
                    SHUF2(m + 2, sya, syb, wpY);
                    hya = ROWLD(sya); hyb = ROWLD(syb);
                }
            }
        }
    };
    run_range(se.x, md);   // phase A: src < 25000 (lower 6.4MB of hb)
    run_range(md, se.y);   // phase B: src >= 25000

    const float inv = 1.f / (den + 1e-16f);
    const size_t o8 = (size_t)n * D + ql * 8;
    float xi[8];
    if constexpr (IN_BF16) {
        const uint4 xv = *(const uint4*)((const unsigned short*)x_in + o8);
        xi[0] = __uint_as_float(xv.x << 16);
        xi[1] = __uint_as_float(xv.x & 0xFFFF0000u);
        xi[2] = __uint_as_float(xv.y << 16);
        xi[3] = __uint_as_float(xv.y & 0xFFFF0000u);
        xi[4] = __uint_as_float(xv.z << 16);
        xi[5] = __uint_as_float(xv.z & 0xFFFF0000u);
        xi[6] = __uint_as_float(xv.w << 16);
        xi[7] = __uint_as_float(xv.w & 0xFFFF0000u);
    } else {
        const float4 a = *(const float4*)((const float*)x_in + o8);
        const float4 b = *(const float4*)((const float*)x_in + o8 + 4);
        xi[0]=a.x; xi[1]=a.y; xi[2]=a.z; xi[3]=a.w;
        xi[4]=b.x; xi[5]=b.y; xi[6]=b.z; xi[7]=b.w;
    }
    const float4 ba = *(const float4*)(bias + ql * 8);
    const float4 bb = *(const float4*)(bias + ql * 8 + 4);
    const float bi[8] = {ba.x, ba.y, ba.z, ba.w, bb.x, bb.y, bb.z, bb.w};
    float o[8];
    #pragma unroll
    for (int c = 0; c < 8; ++c) {
        float v = fmaf(acc[c], inv, xi[c]) + bi[c];
        if constexpr (ACT) v = (v > 0.f) ? v : (__expf(v) - 1.f);
        o[c] = v;
    }
    if constexpr (OUT_BF16) {
        unsigned short ov[8];
        #pragma unroll
        for (int c = 0; c < 8; ++c) ov[c] = rne_bf16(o[c]);
        *(uint4*)((unsigned short*)out + o8) = *(const uint4*)ov;
    } else {
        float4 oa = {o[0], o[1], o[2], o[3]};
        float4 ob = {o[4], o[5], o[6], o[7]};
        *(float4*)((float*)out + o8)     = oa;
        *(float4*)((float*)out + o8 + 4) = ob;
    }
}

// ---------------------------------------------------------------------------
extern "C" void kernel_launch(void* const* d_in, const int* in_sizes, int n_in,
                              void* d_out, int out_size, void* d_ws, size_t ws_size,
                              hipStream_t stream) {
    const float* x     = (const float*)d_in[0];
    const int*   ei    = (const int*)d_in[1];
    const float* W     = (const float*)d_in[2];
    const float* a_src = (const float*)d_in[3];
    const float* a_dst = (const float*)d_in[4];
    const float* bias  = (const float*)d_in[5];
    float* outp = (float*)d_out;

    const int* e_src = ei;
    const int* e_dst = ei + NE;

    // workspace layout (bytes)
    char* base = (char*)d_ws;
    unsigned short* hb  = (unsigned short*)(base);             // NN*D bf16 (12.8MB)
    unsigned short* x1b = (unsigned short*)(base + 12800000);  // NN*D bf16 (12.8MB)
    float* al_s      = (float*)(base + 25600000);              // NN*NH
    float* al_d      = (float*)(base + 26400000);              // NN*NH
    int2*  rowse     = (int2*) (base + 27200000);              // NN int2 (400KB)
    int*   midp      = (int*)  (base + 27600064);              // NN int (200KB)
    unsigned short* srcs = (unsigned short*)(base + 27800064); // NBUK*CAPS (1.81MB)
    unsigned* outbuf = (unsigned*)(base + 29606400);           // NPB*EPB uint (3.2MB)
    int* cnts        = (int*)  (base + 32809472);              // NBUK*NPB (306KB)
    int* lofs        = (int*)  (base + 33116016);              // NBUK*NPB (306KB)
    unsigned short* Wpk = (unsigned short*)(base + 33422560);  // 2*2304*8 bf16 (72KB)

    // K1: repack ∥ partition (both stateless, no pre-zeroed memory)
    prep_kernel<<<RBLK + NPB, 256, 0, stream>>>(W, a_src, a_dst, Wpk,
                                                e_src, e_dst, outbuf, cnts, lofs);

    const int gemm_blocks   = (NN + 63) / 64;   // 782
    const int gather_blocks = (NN + 15) / 16;

    // K2: bucket_sort 512-bin (196 blocks) ∥ gemm layer 0 (782 blocks)
    sort_gemm_kernel<0><<<NBUK + gemm_blocks, 256, 0, stream>>>(
        outbuf, cnts, lofs, rowse, midp, srcs, x, Wpk, hb, al_s, al_d);

    // K3: gather layer 0
    gather_kernel<0, 1, 1><<<gather_blocks, 256, 0, stream>>>(
        hb, al_s, al_d, rowse, midp, srcs, x, bias, x1b);

    // K4: gemm layer 1
    gemm_alpha_kernel<1><<<gemm_blocks, 256, 0, stream>>>(
        x1b, Wpk + (size_t)FR_PER_LAYER * 8, hb, al_s, al_d);

    // K5: gather layer 1
    gather_kernel<1, 0, 0><<<gather_blocks, 256, 0, stream>>>(
        hb, al_s, al_d, rowse, midp, srcs, x1b, bias + D, outp);
}

// Round 14
// 125.012 us; speedup vs baseline: 1.0335x; 1.0335x over previous
//
#include <hip/hip_runtime.h>
#include <math.h>

// GAT 2-layer forward. N=50000 nodes, E=800000 edges, D=128, H=4 heads, F=32.
constexpr int NN = 50000;
constexpr int NE = 800000;
constexpr int D  = 128;
constexpr int NH = 4;
constexpr int NBUK = (NN + 255) / 256;   // 196 dst-range buckets of 256 nodes
constexpr int EPB  = 2048;               // edges per partition block
constexpr int NPB  = (NE + EPB - 1) / EPB;  // 391
constexpr int CAPS = 4608;               // srcs per-bucket stride (mean 4082 + 8σ)
constexpr int FR_PER_LAYER = 9 * 4 * 64; // 9 B-tiles (8 W + 1 alpha-C) per layer
constexpr int RBLK = (2 * FR_PER_LAYER) / 256;   // 18 repack blocks (exact)

typedef __attribute__((ext_vector_type(8))) short short8v;  // 8 bf16 (4 VGPR)
typedef __attribute__((ext_vector_type(4))) float f32x4;    // MFMA accumulator

__device__ inline unsigned short rne_bf16(float f) {
    unsigned bits = __float_as_uint(f);
    return (unsigned short)((bits + 0x7FFFu + ((bits >> 16) & 1u)) >> 16);
}

// acc += a.bf16[0]*b.bf16[0] + a.bf16[1]*b.bf16[1]  (f32 accumulate)
#define DOT2BF(accv, pa, pb) \
    asm("v_dot2_f32_bf16 %0, %1, %2, %0" : "+v"(accv) : "v"(pa), "v"(pb))

// ============== K1: repack ∥ partition (fused, no global atomics) ===========
__device__ __forceinline__ void repack_body(
    int tid, const float* __restrict__ W, const float* __restrict__ a_src,
    const float* __restrict__ a_dst, unsigned short* __restrict__ Wpk)
{
    int layer = tid / FR_PER_LAYER;
    int rest  = tid % FR_PER_LAYER;
    int tile  = rest >> 8;            // 0..8
    int kstep = (rest >> 6) & 3;
    int lane  = rest & 63;
    int col   = lane & 15;
    int kbase = kstep * 32 + (lane >> 4) * 8;
    const float* Wl = W + (size_t)layer * D * D;
    unsigned short v[8];
    if (tile < 8) {
        int c = tile * 16 + col;
        #pragma unroll
        for (int j = 0; j < 8; ++j) v[j] = rne_bf16(Wl[(kbase + j) * D + c]);
    } else {
        #pragma unroll
        for (int j = 0; j < 8; ++j) v[j] = 0;
        if (col < 8) {
            const float* av = ((col < 4) ? a_src : a_dst) + layer * D + (col & 3) * 32;
            const int hbase = (col & 3) * 32;
            for (int j = 0; j < 8; ++j) {
                float sum = 0.f;
                const float* wr = Wl + (size_t)(kbase + j) * D + hbase;
                #pragma unroll
                for (int jj = 0; jj < 32; ++jj) sum = fmaf(wr[jj], av[jj], sum);
                v[j] = rne_bf16(sum);
            }
        }
    }
    *(uint4*)(Wpk + (size_t)tid * 8) = *(const uint4*)v;
}

__global__ __launch_bounds__(256) void prep_kernel(
    const float* __restrict__ W, const float* __restrict__ a_src,
    const float* __restrict__ a_dst, unsigned short* __restrict__ Wpk,
    const int* __restrict__ src, const int* __restrict__ dst,
    unsigned* __restrict__ outbuf, int* __restrict__ cnts,
    int* __restrict__ lofs)
{
    __shared__ union {
        struct { unsigned stage[EPB]; int cnt[NBUK]; int fill[NBUK]; int sc[256]; } p;
        int dummy;
    } sm;
    if (blockIdx.x < RBLK) {
        repack_body(blockIdx.x * 256 + threadIdx.x, W, a_src, a_dst, Wpk);
        return;
    }
    const int pb = blockIdx.x - RBLK;
    const int t  = threadIdx.x;
    for (int i = t; i < NBUK; i += 256) sm.p.cnt[i] = 0;
    __syncthreads();
    const int base = pb * EPB;
    const int tot  = min(NE - base, EPB);
    unsigned pk[8]; int bk[8];
    #pragma unroll
    for (int i = 0; i < 8; ++i) {
        int e = base + i * 256 + t;
        bool ok = (e < NE);
        int s = ok ? src[e] : 0;
        int d = ok ? dst[e] : 0;
        bk[i] = d >> 8;
        pk[i] = (unsigned)s | ((unsigned)(d & 255) << 16) | ((unsigned)bk[i] << 24);
        if (ok) atomicAdd(&sm.p.cnt[bk[i]], 1);
    }
    __syncthreads();
    int v = (t < NBUK) ? sm.p.cnt[t] : 0;
    sm.p.sc[t] = v;
    __syncthreads();
    for (int off = 1; off < 256; off <<= 1) {
        int u = (t >= off) ? sm.p.sc[t - off] : 0;
        __syncthreads();
        sm.p.sc[t] += u;
        __syncthreads();
    }
    const int excl = sm.p.sc[t] - v;
    if (t < NBUK) {
        sm.p.fill[t] = excl;
        cnts[t * NPB + pb] = v;      // [bucket][block] -> coalesced sort reads
        lofs[t * NPB + pb] = excl;
    }
    __syncthreads();
    #pragma unroll
    for (int i = 0; i < 8; ++i) {
        int e = base + i * 256 + t;
        if (e < NE) {
            int pos = atomicAdd(&sm.p.fill[bk[i]], 1);
            sm.p.stage[pos] = pk[i];
        }
    }
    __syncthreads();
    for (int i = t; i < tot; i += 256) outbuf[base + i] = sm.p.stage[i];
}

// ---------------- gemm body: h = x @ W via MFMA; alphas via C tile ----------
template<int BF16IN>
__device__ __forceinline__ void gemm_body(
    int blk, unsigned short* __restrict__ xl, const void* __restrict__ xin,
    const unsigned short* __restrict__ Wpk, unsigned short* __restrict__ hb,
    float* __restrict__ alpha_s, float* __restrict__ alpha_d)
{
    const int t = threadIdx.x;
    const int row0 = blk * 64;

    if constexpr (BF16IN) {
        const unsigned short* xb = (const unsigned short*)xin;
        #pragma unroll
        for (int it = 0; it < 4; ++it) {
            int idx = it * 256 + t;
            int r   = idx >> 4;
            int c8  = (idx & 15) * 8;
            int n   = row0 + r;
            uint4 v = {0u, 0u, 0u, 0u};
            if (n < NN) v = *(const uint4*)(xb + (size_t)n * D + c8);
            *(uint4*)(xl + r * 128 + (c8 ^ ((r & 7) << 3))) = v;
        }
    } else {
        const float* xf = (const float*)xin;
        #pragma unroll
        for (int it = 0; it < 8; ++it) {
            int idx = it * 256 + t;
            int r   = idx >> 5;
            int c4  = (idx & 31) * 4;
            int n   = row0 + r;
            float4 v;
            if (n < NN) v = *(const float4*)(xf + (size_t)n * D + c4);
            else { v.x = 0.f; v.y = 0.f; v.z = 0.f; v.w = 0.f; }
            unsigned p0 = ((unsigned)rne_bf16(v.y) << 16) | rne_bf16(v.x);
            unsigned p1 = ((unsigned)rne_bf16(v.w) << 16) | rne_bf16(v.z);
            uint2 pv; pv.x = p0; pv.y = p1;
            *(uint2*)(xl + r * 128 + (c4 ^ ((r & 7) << 3))) = pv;
        }
    }
    __syncthreads();

    const int wv  = t >> 6;
    const int l   = t & 63;
    const int l15 = l & 15;
    const int g   = l >> 4;
    const int strip = wv * 16;
    const int arow  = strip + l15;

    f32x4 acc[9];
    #pragma unroll
    for (int i = 0; i < 9; ++i) acc[i] = (f32x4){0.f, 0.f, 0.f, 0.f};

    #pragma unroll
    for (int ks = 0; ks < 4; ++ks) {
        const int k0 = ks * 32 + g * 8;
        short8v a = *(const short8v*)(xl + arow * 128 + (k0 ^ ((arow & 7) << 3)));
        #pragma unroll
        for (int tl = 0; tl < 9; ++tl) {
            short8v b = *(const short8v*)(Wpk + ((size_t)(tl * 4 + ks) * 64 + l) * 8);
            acc[tl] = __builtin_amdgcn_mfma_f32_16x16x32_bf16(a, b, acc[tl], 0, 0, 0);
        }
    }

    #pragma unroll
    for (int r = 0; r < 4; ++r) {
        const int n = row0 + strip + g * 4 + r;
        if (n < NN) {
            #pragma unroll
            for (int tl = 0; tl < 8; ++tl)
                hb[(size_t)n * D + tl * 16 + l15] = rne_bf16(acc[tl][r]);
            const float av = acc[8][r];
            if (l15 < 4)      alpha_s[n * NH + l15]       = av;
            else if (l15 < 8) alpha_d[n * NH + (l15 - 4)] = av;
        }
    }
}

// ============== K2: bucket_sort ∥ gemm-L0 (fused) ===========================
template<int BF16IN>
__global__ __launch_bounds__(256) void sort_gemm_kernel(
    const unsigned* __restrict__ outbuf, const int* __restrict__ cnts,
    const int* __restrict__ lofs, int2* __restrict__ rowse,
    unsigned short* __restrict__ srcs, const void* __restrict__ xin,
    const unsigned short* __restrict__ Wpk, unsigned short* __restrict__ hb,
    float* __restrict__ alpha_s, float* __restrict__ alpha_d)
{
    __shared__ union {
        struct { unsigned stage[CAPS]; int hist[256]; int run[256]; int sc[256]; int cursor; } s;
        unsigned short xl[64 * 128];
    } sm;

    if (blockIdx.x >= NBUK) {
        gemm_body<BF16IN>(blockIdx.x - NBUK, sm.xl, xin, Wpk, hb, alpha_s, alpha_d);
        return;
    }
    const int b = blockIdx.x;
    const int t = threadIdx.x;
    if (t == 0) sm.s.cursor = 0;
    sm.s.hist[t] = 0;
    __syncthreads();
    // copy phase: pull this bucket's segment from each partition-block region
    for (int pb = t; pb < NPB; pb += 256) {
        int len = cnts[b * NPB + pb];
        if (len > 0) {
            int off = lofs[b * NPB + pb];
            int pos = atomicAdd(&sm.s.cursor, len);
            const unsigned* sp = outbuf + pb * EPB + off;
            for (int k = 0; k < len; ++k)
                if (pos + k < CAPS) sm.s.stage[pos + k] = sp[k];
        }
    }
    __syncthreads();
    const int tot = min(sm.s.cursor, CAPS);
    for (int i = t; i < tot; i += 256)
        atomicAdd(&sm.s.hist[(sm.s.stage[i] >> 16) & 255], 1);
    __syncthreads();
    int v = sm.s.hist[t];
    sm.s.sc[t] = v;
    __syncthreads();
    for (int off = 1; off < 256; off <<= 1) {
        int u = (t >= off) ? sm.s.sc[t - off] : 0;
        __syncthreads();
        sm.s.sc[t] += u;
        __syncthreads();
    }
    const int excl = sm.s.sc[t] - v;
    const int node = b * 256 + t;
    if (node < NN) {
        int2 se; se.x = b * CAPS + excl; se.y = b * CAPS + excl + v;
        rowse[node] = se;
    }
    sm.s.run[t] = excl;
    __syncthreads();
    for (int i = t; i < tot; i += 256) {
        unsigned p = sm.s.stage[i];
        int pos = atomicAdd(&sm.s.run[(p >> 16) & 255], 1);
        srcs[b * CAPS + pos] = (unsigned short)(p & 0xFFFFu);
    }
}

// Standalone gemm for layer 1
template<int BF16IN>
__global__ __launch_bounds__(256) void gemm_alpha_kernel(
    const void* __restrict__ xin, const unsigned short* __restrict__ Wpk,
    unsigned short* __restrict__ hb, float* __restrict__ alpha_s,
    float* __restrict__ alpha_d)
{
    __shared__ unsigned short xl[64 * 128];
    gemm_body<BF16IN>(blockIdx.x, xl, xin, Wpk, hb, alpha_s, alpha_d);
}

// ---------------- per-dst-node gather + softmax + aggregate + epilogue ------
// Quarter-wave per node; lane owns 8 cols; 2 edges/iter via v_perm_b32 +
// v_dot2_f32_bf16; 2-slot software pipeline. (Fetch-bound at ~hb×8 XCDs.)
#define SHUF2(MI, SA, SB, WP) {                                          \
    int eA = lb + (MI), eB = eA + 1;                                     \
    SA = __shfl(msrc, eA); SB = __shfl(msrc, eB);                        \
    unsigned a01 = (unsigned)__shfl((int)uw01, eA);                      \
    unsigned a23 = (unsigned)__shfl((int)uw23, eA);                      \
    unsigned c01 = (unsigned)__shfl((int)uw01, eB);                      \
    unsigned c23 = (unsigned)__shfl((int)uw23, eB);                      \
    unsigned uwA = (head < 2) ? a01 : a23;                               \
    unsigned uwB = (head < 2) ? c01 : c23;                               \
    WP = __builtin_amdgcn_perm(uwB, uwA, wsel); }

#define ROWLD(S) (*(const uint4*)(hb + ((size_t)(S) << 7) + (ql << 3)))

#define DOT2BLOCK(WP, HA, HB) {                                               \
    DOT2BF(den, WP, ones);                                                    \
    unsigned p_;                                                              \
    p_ = __builtin_amdgcn_perm(HB.x, HA.x, 0x05040100u); DOT2BF(acc[0], p_, WP); \
    p_ = __builtin_amdgcn_perm(HB.x, HA.x, 0x07060302u); DOT2BF(acc[1], p_, WP); \
    p_ = __builtin_amdgcn_perm(HB.y, HA.y, 0x05040100u); DOT2BF(acc[2], p_, WP); \
    p_ = __builtin_amdgcn_perm(HB.y, HA.y, 0x07060302u); DOT2BF(acc[3], p_, WP); \
    p_ = __builtin_amdgcn_perm(HB.z, HA.z, 0x05040100u); DOT2BF(acc[4], p_, WP); \
    p_ = __builtin_amdgcn_perm(HB.z, HA.z, 0x07060302u); DOT2BF(acc[5], p_, WP); \
    p_ = __builtin_amdgcn_perm(HB.w, HA.w, 0x05040100u); DOT2BF(acc[6], p_, WP); \
    p_ = __builtin_amdgcn_perm(HB.w, HA.w, 0x07060302u); DOT2BF(acc[7], p_, WP); }

template<int IN_BF16, int OUT_BF16, int ACT>
__global__ __launch_bounds__(256) void gather_kernel(
    const unsigned short* __restrict__ hb, const float* __restrict__ alpha_s,
    const float* __restrict__ alpha_d, const int2* __restrict__ rowse,
    const unsigned short* __restrict__ srcs, const void* __restrict__ x_in,
    const float* __restrict__ bias, void* __restrict__ out)
{
    const int lane = threadIdx.x & 63;
    const int q    = lane >> 4;
    const int ql   = lane & 15;
    const int head = ql >> 2;
    const int lb   = q * 16;
    const int n = blockIdx.x * 16 + (threadIdx.x >> 6) * 4 + q;
    if (n >= NN) return;

    const int2 se = rowse[n];
    const int start = se.x, end = se.y;
    const float4 ad4 = *(const float4*)&alpha_d[n * NH];
    const unsigned wsel = (head & 1) ? 0x07060302u : 0x05040100u;
    const unsigned ones = 0x3F803F80u;

    float acc[8];
    #pragma unroll
    for (int c = 0; c < 8; ++c) acc[c] = 0.f;
    float den = 0.f;

    for (int base = start; base < end; base += 16) {
        const int cnt = min(16, end - base);
        int msrc = 0;
        unsigned uw01 = 0, uw23 = 0;
        if (ql < cnt) {
            msrc = srcs[base + ql];
            const float4 as4 = *(const float4*)&alpha_s[msrc * NH];
            float e0 = as4.x + ad4.x; e0 = (e0 > 0.f) ? e0 : 0.2f * e0;
            float e1 = as4.y + ad4.y; e1 = (e1 > 0.f) ? e1 : 0.2f * e1;
            float e2 = as4.z + ad4.z; e2 = (e2 > 0.f) ? e2 : 0.2f * e2;
            float e3 = as4.w + ad4.w; e3 = (e3 > 0.f) ? e3 : 0.2f * e3;
            float w0 = __expf(e0), w1 = __expf(e1);
            float w2 = __expf(e2), w3 = __expf(e3);
            uw01 = ((unsigned)rne_bf16(w1) << 16) | rne_bf16(w0);
            uw23 = ((unsigned)rne_bf16(w3) << 16) | rne_bf16(w2);
        }
        const int mm = (cnt + 1) & ~1;

        int sxa, sxb, sya, syb;
        unsigned wpX, wpY;
        uint4 hxa, hxb, hya, hyb;
        SHUF2(0, sxa, sxb, wpX);
        hxa = ROWLD(sxa); hxb = ROWLD(sxb);
        if (mm > 2) {
            SHUF2(2, sya, syb, wpY);
            hya = ROWLD(sya); hyb = ROWLD(syb);
        }
        int m = 0;
        while (true) {
            DOT2BLOCK(wpX, hxa, hxb);
            m += 2;
            if (m >= mm) break;
            if (m + 2 < mm) {
                SHUF2(m + 2, sxa, sxb, wpX);
                hxa = ROWLD(sxa); hxb = ROWLD(sxb);
            }
            DOT2BLOCK(wpY, hya, hyb);
            m += 2;
            if (m >= mm) break;
            if (m + 2 < mm) {
                SHUF2(m + 2, sya, syb, wpY);
                hya = ROWLD(sya); hyb = ROWLD(syb);
            }
        }
    }

    const float inv = 1.f / (den + 1e-16f);
    const size_t o8 = (size_t)n * D + ql * 8;
    float xi[8];
    if constexpr (IN_BF16) {
        const uint4 xv = *(const uint4*)((const unsigned short*)x_in + o8);
        xi[0] = __uint_as_float(xv.x << 16);
        xi[1] = __uint_as_float(xv.x & 0xFFFF0000u);
        xi[2] = __uint_as_float(xv.y << 16);
        xi[3] = __uint_as_float(xv.y & 0xFFFF0000u);
        xi[4] = __uint_as_float(xv.z << 16);
        xi[5] = __uint_as_float(xv.z & 0xFFFF0000u);
        xi[6] = __uint_as_float(xv.w << 16);
        xi[7] = __uint_as_float(xv.w & 0xFFFF0000u);
    } else {
        const float4 a = *(const float4*)((const float*)x_in + o8);
        const float4 b = *(const float4*)((const float*)x_in + o8 + 4);
        xi[0]=a.x; xi[1]=a.y; xi[2]=a.z; xi[3]=a.w;
        xi[4]=b.x; xi[5]=b.y; xi[6]=b.z; xi[7]=b.w;
    }
    const float4 ba = *(const float4*)(bias + ql * 8);
    const float4 bb = *(const float4*)(bias + ql * 8 + 4);
    const float bi[8] = {ba.x, ba.y, ba.z, ba.w, bb.x, bb.y, bb.z, bb.w};
    float o[8];
    #pragma unroll
    for (int c = 0; c < 8; ++c) {
        float v = fmaf(acc[c], inv, xi[c]) + bi[c];
        if constexpr (ACT) v = (v > 0.f) ? v : (__expf(v) - 1.f);
        o[c] = v;
    }
    if constexpr (OUT_BF16) {
        unsigned short ov[8];
        #pragma unroll
        for (int c = 0; c < 8; ++c) ov[c] = rne_bf16(o[c]);
        *(uint4*)((unsigned short*)out + o8) = *(const uint4*)ov;
    } else {
        float4 oa = {o[0], o[1], o[2], o[3]};
        float4 ob = {o[4], o[5], o[6], o[7]};
        *(float4*)((float*)out + o8)     = oa;
        *(float4*)((float*)out + o8 + 4) = ob;
    }
}

// ---------------------------------------------------------------------------
extern "C" void kernel_launch(void* const* d_in, const int* in_sizes, int n_in,
                              void* d_out, int out_size, void* d_ws, size_t ws_size,
                              hipStream_t stream) {
    const float* x     = (const float*)d_in[0];
    const int*   ei    = (const int*)d_in[1];
    const float* W     = (const float*)d_in[2];
    const float* a_src = (const float*)d_in[3];
    const float* a_dst = (const float*)d_in[4];
    const float* bias  = (const float*)d_in[5];
    float* outp = (float*)d_out;

    const int* e_src = ei;
    const int* e_dst = ei + NE;

    // workspace layout (bytes)
    char* base = (char*)d_ws;
    unsigned short* hb  = (unsigned short*)(base);             // NN*D bf16 (12.8MB)
    unsigned short* x1b = (unsigned short*)(base + 12800000);  // NN*D bf16 (12.8MB)
    float* al_s      = (float*)(base + 25600000);              // NN*NH
    float* al_d      = (float*)(base + 26400000);              // NN*NH
    int2*  rowse     = (int2*) (base + 27200000);              // NN int2 (400KB)
    unsigned short* srcs = (unsigned short*)(base + 27600000); // NBUK*CAPS (1.81MB)
    unsigned* outbuf = (unsigned*)(base + 29406336);           // NPB*EPB uint (3.2MB)
    int* cnts        = (int*)  (base + 32609408);              // NBUK*NPB (306KB)
    int* lofs        = (int*)  (base + 32915952);              // NBUK*NPB (306KB)
    unsigned short* Wpk = (unsigned short*)(base + 33222496);  // 2*2304*8 bf16 (72KB)

    // K1: repack ∥ partition (both stateless, no pre-zeroed memory)
    prep_kernel<<<RBLK + NPB, 256, 0, stream>>>(W, a_src, a_dst, Wpk,
                                                e_src, e_dst, outbuf, cnts, lofs);

    const int gemm_blocks   = (NN + 63) / 64;   // 782
    const int gather_blocks = (NN + 15) / 16;

    // K2: bucket_sort (196 blocks) ∥ gemm layer 0 (782 blocks)
    sort_gemm_kernel<0><<<NBUK + gemm_blocks, 256, 0, stream>>>(
        outbuf, cnts, lofs, rowse, srcs, x, Wpk, hb, al_s, al_d);

    // K3: gather layer 0
    gather_kernel<0, 1, 1><<<gather_blocks, 256, 0, stream>>>(
        hb, al_s, al_d, rowse, srcs, x, bias, x1b);

    // K4: gemm layer 1
    gemm_alpha_kernel<1><<<gemm_blocks, 256, 0, stream>>>(
        x1b, Wpk + (size_t)FR_PER_LAYER * 8, hb, al_s, al_d);

    // K5: gather layer 1
    gather_kernel<1, 0, 0><<<gather_blocks, 256, 0, stream>>>(
        hb, al_s, al_d, rowse, srcs, x1b, bias + D, outp);
}